// Round 5
// baseline (164.713 us; speedup 1.0000x reference)
//
#include <hip/hip_runtime.h>
#include <hip/hip_bf16.h>
#include <cstdint>

// LSTM cell: B=8192, D=1024, U=1024.
// z = [X|H](8192x2048) @ Wcat(2048x4096), gate interleave 16 in N, fused epilogue.
// GEMM: 256x256 tile, BK=32, 8 waves (2Mx4N), 512 thr, triple-buffered LDS,
// register-prefetched fragments (1 tile ahead), ONE barrier per K-tile,
// issue-early/drain-late vmcnt, setprio around MFMA clusters, XOR LDS swizzle.

using f32x4  = __attribute__((ext_vector_type(4))) float;
using short8 = __attribute__((ext_vector_type(8))) short;

__device__ __forceinline__ unsigned short f2bf(float f) {
  union { float f; unsigned int u; } v; v.f = f;
  unsigned int r = v.u + 0x7fffu + ((v.u >> 16) & 1u);  // RNE
  return (unsigned short)(r >> 16);
}
__device__ __forceinline__ float sigmoidf_fast(float x) { return 1.f / (1.f + __expf(-x)); }
__device__ __forceinline__ float tanhf_fast(float x)    { return 1.f - 2.f / (__expf(2.f * x) + 1.f); }

// ---------- A conversion: Abf[b][k] = bf16(k<1024 ? X[b][k] : H[b][k-1024])
__global__ void conv_a_kernel(const float* __restrict__ X, const float* __restrict__ H,
                              unsigned short* __restrict__ Abf) {
  int idx = blockIdx.x * blockDim.x + threadIdx.x;
  int b  = idx >> 8;
  int kq = (idx & 255) << 2;
  float4 x = *(const float4*)(X + (long)b * 1024 + kq);
  float4 h = *(const float4*)(H + (long)b * 1024 + kq);
  ushort4 xo, ho;
  xo.x = f2bf(x.x); xo.y = f2bf(x.y); xo.z = f2bf(x.z); xo.w = f2bf(x.w);
  ho.x = f2bf(h.x); ho.y = f2bf(h.y); ho.z = f2bf(h.z); ho.w = f2bf(h.w);
  *(ushort4*)(Abf + (long)b * 2048 + kq)        = xo;
  *(ushort4*)(Abf + (long)b * 2048 + 1024 + kq) = ho;
}

// ---------- B conversion: Bt[n][k] bf16, N-major, n = (u>>4)*64 + g*16 + (u&15)
__global__ void conv_b_kernel(const float* W_i, const float* U_i,
                              const float* W_f, const float* U_f,
                              const float* W_c, const float* U_c,
                              const float* W_o, const float* U_o,
                              unsigned short* __restrict__ Bt) {
  __shared__ float tile[64][65];
  int z = blockIdx.z;
  const float* src;
  switch (z) {
    case 0: src = W_i; break; case 1: src = U_i; break;
    case 2: src = W_f; break; case 3: src = U_f; break;
    case 4: src = W_c; break; case 5: src = U_c; break;
    case 6: src = W_o; break; default: src = U_o; break;
  }
  int g = z >> 1, s = z & 1;
  int k0 = blockIdx.x * 64;
  int u0 = blockIdx.y * 64;
  int t = threadIdx.x;
  int c = t & 63, r0 = t >> 6;
#pragma unroll
  for (int i = 0; i < 16; ++i) {
    int r = i * 4 + r0;
    tile[r][c] = src[(long)(k0 + r) * 1024 + u0 + c];
  }
  __syncthreads();
  int ul = t >> 2;
  int ks = (t & 3) * 16;
  unsigned short outv[16];
#pragma unroll
  for (int j = 0; j < 16; ++j) outv[j] = f2bf(tile[ks + j][ul]);
  long n   = 4L * u0 + (ul >> 4) * 64 + g * 16 + (ul & 15);
  long col = (long)s * 1024 + k0 + ks;
  uint4* dst = (uint4*)(Bt + n * 2048 + col);
  dst[0] = *(uint4*)(outv);
  dst[1] = *(uint4*)(outv + 8);
}

// ---------- fused GEMM + LSTM epilogue
__global__ __launch_bounds__(512, 2) void lstm_gemm_kernel(
    const unsigned short* __restrict__ Abf,   // [8192][2048] bf16
    const unsigned short* __restrict__ Btbf,  // [4096][2048] bf16 (N-major)
    const float* __restrict__ b_i, const float* __restrict__ b_f,
    const float* __restrict__ b_c, const float* __restrict__ b_o,
    const float* __restrict__ c_tm1,
    float* __restrict__ outH, float* __restrict__ outC) {
  // 3 buffers x (A tile 256x32 + B tile 256x32) bf16 = 96KB
  __shared__ unsigned short smem[3 * 16384];

  int bid = blockIdx.x;
  int swz = (bid & 7) * 64 + (bid >> 3);  // XCD swizzle, 512 % 8 == 0
  int bm = swz >> 4;   // 32 m-blocks
  int bn = swz & 15;   // 16 n-blocks

  int t = threadIdx.x;
  int lane = t & 63;
  int w = t >> 6;           // 8 waves
  int wm = w >> 2;          // 0..1
  int wn = w & 3;           // 0..3
  int rl = lane & 15;
  int kg = lane >> 4;       // 0..3, 8-elem k-chunk

  // ---- ds_read element offsets (XOR chunk swizzle: chunk ^= (row>>1)&3) ----
#define AOFF(MI) ((wm * 128 + (MI) * 16 + rl) * 32 + \
    ((((kg * 16) ^ ((((wm * 128 + (MI) * 16 + rl) >> 1) & 3) << 4))) >> 1))
#define BOFF(NI) ((wn * 64 + (NI) * 16 + rl) * 32 + \
    ((((kg * 16) ^ ((((wn * 64 + (NI) * 16 + rl) >> 1) & 3) << 4))) >> 1))
  const int offA0 = AOFF(0), offA1 = AOFF(1), offA2 = AOFF(2), offA3 = AOFF(3);
  const int offA4 = AOFF(4), offA5 = AOFF(5), offA6 = AOFF(6), offA7 = AOFF(7);
  const int offB0 = 8192 + BOFF(0), offB1 = 8192 + BOFF(1);
  const int offB2 = 8192 + BOFF(2), offB3 = 8192 + BOFF(3);
#undef AOFF
#undef BOFF

  // ---- staging: linear LDS dest, inverse-swizzled global source ----
  int srow = t >> 2;
  int cbe  = (((t & 3) * 16) ^ (((srow >> 1) & 3) << 4)) >> 1;
  const unsigned short* aS0 = Abf  + (long)(bm * 256 + srow) * 2048 + cbe;
  const unsigned short* aS1 = aS0 + 128L * 2048;
  const unsigned short* bS0 = Btbf + (long)(bn * 256 + srow) * 2048 + cbe;
  const unsigned short* bS1 = bS0 + 128L * 2048;
  const int dstA0 = t * 8, dstA1 = 4096 + t * 8;
  const int dstB0 = 8192 + t * 8, dstB1 = 12288 + t * 8;

#define GLL(SRC, SB, DOFF)                                                                     \
  __builtin_amdgcn_global_load_lds((const __attribute__((address_space(1))) void*)(SRC),       \
      (__attribute__((address_space(3))) void*)(&smem[(SB) * 16384 + (DOFF)]), 16, 0, 0)

  f32x4 acc[8][4];
#pragma unroll
  for (int mi = 0; mi < 8; ++mi)
#pragma unroll
    for (int ni = 0; ni < 4; ++ni) acc[mi][ni] = (f32x4){0.f, 0.f, 0.f, 0.f};

  // fragment register sets: p (even tiles), q (odd tiles); ah = A rows 4-7, read in-tile
  short8 pa0, pa1, pa2, pa3, pb0, pb1, pb2, pb3;
  short8 qa0, qa1, qa2, qa3, qb0, qb1, qb2, qb3;
  short8 ah0, ah1, ah2, ah3;

  // ---- prologue: stage tiles 0 (buf0) and 1 (buf1); land tile 0; prefetch tile-0 frags ----
  GLL(aS0, 0, dstA0); GLL(aS1, 0, dstA1); GLL(bS0, 0, dstB0); GLL(bS1, 0, dstB1);
  GLL(aS0 + 32, 1, dstA0); GLL(aS1 + 32, 1, dstA1);
  GLL(bS0 + 32, 1, dstB0); GLL(bS1 + 32, 1, dstB1);
  asm volatile("s_waitcnt vmcnt(4)" ::: "memory");
  __builtin_amdgcn_s_barrier();
  pa0 = *(const short8*)(smem + offA0);
  pa1 = *(const short8*)(smem + offA1);
  pa2 = *(const short8*)(smem + offA2);
  pa3 = *(const short8*)(smem + offA3);
  pb0 = *(const short8*)(smem + offB0);
  pb1 = *(const short8*)(smem + offB1);
  pb2 = *(const short8*)(smem + offB2);
  pb3 = *(const short8*)(smem + offB3);
  aS0 += 64; aS1 += 64; bS0 += 64; bS1 += 64;   // staging base -> tile 2

#define MF4(AF, MI, BP)                                                                      \
  acc[MI][0] = __builtin_amdgcn_mfma_f32_16x16x32_bf16(AF, BP##0, acc[MI][0], 0, 0, 0);      \
  acc[MI][1] = __builtin_amdgcn_mfma_f32_16x16x32_bf16(AF, BP##1, acc[MI][1], 0, 0, 0);      \
  acc[MI][2] = __builtin_amdgcn_mfma_f32_16x16x32_bf16(AF, BP##2, acc[MI][2], 0, 0, 0);      \
  acc[MI][3] = __builtin_amdgcn_mfma_f32_16x16x32_bf16(AF, BP##3, acc[MI][3], 0, 0, 0);

// Tile T: consume set C (prefetched during T-1) + ah (read here); prefetch set N.
// C/N are register-set prefixes: C##a0 -> pa0 etc. One barrier per tile.
#define ITER(BUF, STG, NXT, KOFF, C, N, DOSTAGE, DOPREF, DOSYNC)               \
  do {                                                                         \
    const unsigned short* Sr_ = smem + (BUF) * 16384;                          \
    ah0 = *(const short8*)(Sr_ + offA4);                                       \
    ah1 = *(const short8*)(Sr_ + offA5);                                       \
    ah2 = *(const short8*)(Sr_ + offA6);                                       \
    ah3 = *(const short8*)(Sr_ + offA7);                                       \
    __builtin_amdgcn_sched_barrier(0);                                         \
    __builtin_amdgcn_s_setprio(1);                                             \
    MF4(C##a0, 0, C##b) MF4(C##a1, 1, C##b)                                    \
    MF4(C##a2, 2, C##b) MF4(C##a3, 3, C##b)                                    \
    __builtin_amdgcn_s_setprio(0);                                             \
    __builtin_amdgcn_sched_barrier(0);                                         \
    if (DOSYNC) {                                                              \
      asm volatile("s_waitcnt vmcnt(0)" ::: "memory");                         \
      __builtin_amdgcn_s_barrier();                                            \
      __builtin_amdgcn_sched_barrier(0);                                       \
    }                                                                          \
    if (DOSTAGE) {                                                             \
      GLL(aS0 + (KOFF), (STG), dstA0); GLL(aS1 + (KOFF), (STG), dstA1);        \
      GLL(bS0 + (KOFF), (STG), dstB0); GLL(bS1 + (KOFF), (STG), dstB1);        \
    }                                                                          \
    if (DOPREF) {                                                              \
      const unsigned short* Sn_ = smem + (NXT) * 16384;                        \
      N##a0 = *(const short8*)(Sn_ + offA0);                                   \
      N##a1 = *(const short8*)(Sn_ + offA1);                                   \
      N##a2 = *(const short8*)(Sn_ + offA2);                                   \
      N##a3 = *(const short8*)(Sn_ + offA3);                                   \
      N##b0 = *(const short8*)(Sn_ + offB0);                                   \
      N##b1 = *(const short8*)(Sn_ + offB1);                                   \
      N##b2 = *(const short8*)(Sn_ + offB2);                                   \
      N##b3 = *(const short8*)(Sn_ + offB3);                                   \
    }                                                                          \
    __builtin_amdgcn_sched_barrier(0);                                         \
    __builtin_amdgcn_s_setprio(1);                                             \
    MF4(ah0, 4, C##b) MF4(ah1, 5, C##b)                                        \
    MF4(ah2, 6, C##b) MF4(ah3, 7, C##b)                                        \
    __builtin_amdgcn_s_setprio(0);                                             \
  } while (0)

  // Main: 10 groups of 6 tiles (T=0..59); each tile stages T+2, prefetches T+1.
  for (int g = 0; g < 10; ++g) {
    ITER(0, 2, 1, 0,   p, q, 1, 1, 1);
    ITER(1, 0, 2, 32,  q, p, 1, 1, 1);
    ITER(2, 1, 0, 64,  p, q, 1, 1, 1);
    ITER(0, 2, 1, 96,  q, p, 1, 1, 1);
    ITER(1, 0, 2, 128, p, q, 1, 1, 1);
    ITER(2, 1, 0, 160, q, p, 1, 1, 1);
    aS0 += 192; aS1 += 192; bS0 += 192; bS1 += 192;
  }
  // Tail: T=60 (stage 62), 61 (stage 63), 62 (drain + prefetch 63), 63 (pure compute)
  ITER(0, 2, 1, 0,  p, q, 1, 1, 1);
  ITER(1, 0, 2, 32, q, p, 1, 1, 1);
  ITER(2, 0, 0, 0,  p, q, 0, 1, 1);
  ITER(0, 0, 0, 0,  q, p, 0, 0, 0);
#undef ITER
#undef MF4
#undef GLL

  // ---- fused LSTM epilogue ----
  // Wave N-span = 64 cols = one u-block: u = nbase/4 + rl; gate = ni.
  int mbase = bm * 256 + wm * 128;
  int nbase = bn * 256 + wn * 64;
  int u = (nbase >> 2) + rl;
  float bi_v = b_i[u], bf_v = b_f[u], bc_v = b_c[u], bo_v = b_o[u];
  int rquad = (lane >> 4) << 2;
#pragma unroll
  for (int mi = 0; mi < 8; ++mi) {
#pragma unroll
    for (int j = 0; j < 4; ++j) {
      int brow = mbase + mi * 16 + rquad + j;
      float zi = acc[mi][0][j] + bi_v;
      float zf = acc[mi][1][j] + bf_v;
      float zc = acc[mi][2][j] + bc_v;
      float zo = acc[mi][3][j] + bo_v;
      float ig = sigmoidf_fast(zi);
      float fg = sigmoidf_fast(zf);
      float cg = tanhf_fast(zc);
      float og = sigmoidf_fast(zo);
      float cp = c_tm1[(long)brow * 1024 + u];
      float cn = fg * cp + ig * cg;
      float hn = og * tanhf_fast(cn);
      outH[(long)brow * 1024 + u] = hn;
      outC[(long)brow * 1024 + u] = cn;
    }
  }
}

extern "C" void kernel_launch(void* const* d_in, const int* in_sizes, int n_in,
                              void* d_out, int out_size, void* d_ws, size_t ws_size,
                              hipStream_t stream) {
  (void)in_sizes; (void)n_in; (void)out_size; (void)ws_size;
  const float* X   = (const float*)d_in[0];
  const float* Hst = (const float*)d_in[1];
  const float* Cst = (const float*)d_in[2];
  const float* W_i = (const float*)d_in[3];
  const float* U_i = (const float*)d_in[4];
  const float* b_i = (const float*)d_in[5];
  const float* W_f = (const float*)d_in[6];
  const float* U_f = (const float*)d_in[7];
  const float* b_f = (const float*)d_in[8];
  const float* W_c = (const float*)d_in[9];
  const float* U_c = (const float*)d_in[10];
  const float* b_c = (const float*)d_in[11];
  const float* W_o = (const float*)d_in[12];
  const float* U_o = (const float*)d_in[13];
  const float* b_o = (const float*)d_in[14];

  unsigned short* Abf  = (unsigned short*)d_ws;                        // 32 MB
  unsigned short* Btbf = (unsigned short*)((char*)d_ws + 33554432);    // 16 MB

  float* outH = (float*)d_out;
  float* outC = outH + 8192L * 1024;

  conv_a_kernel<<<8192, 256, 0, stream>>>(X, Hst, Abf);
  conv_b_kernel<<<dim3(16, 16, 8), 256, 0, stream>>>(W_i, U_i, W_f, U_f, W_c, U_c, W_o, U_o, Btbf);
  lstm_gemm_kernel<<<512, 512, 0, stream>>>(Abf, Btbf, b_i, b_f, b_c, b_o, Cst, outH, outC);
}

// Round 6
// 158.333 us; speedup vs baseline: 1.0403x; 1.0403x over previous
//
#include <hip/hip_runtime.h>
#include <hip/hip_bf16.h>
#include <cstdint>

// LSTM cell: B=8192, D=1024, U=1024.
// z = [X|H](8192x2048) @ Wcat(2048x4096), gate interleave 16 in N, fused epilogue.
// GEMM: 256x256 tile, BK=32, 8 waves (2Mx4N), 512 thr, QUAD-buffered LDS (128KB),
// prefetch distance 3, counted vmcnt(4) in steady state (T4 — never drain to 0),
// register-prefetched fragments, ONE barrier per K-tile, setprio, XOR LDS swizzle.

using f32x4  = __attribute__((ext_vector_type(4))) float;
using short8 = __attribute__((ext_vector_type(8))) short;

__device__ __forceinline__ unsigned short f2bf(float f) {
  union { float f; unsigned int u; } v; v.f = f;
  unsigned int r = v.u + 0x7fffu + ((v.u >> 16) & 1u);  // RNE
  return (unsigned short)(r >> 16);
}
__device__ __forceinline__ float sigmoidf_fast(float x) { return 1.f / (1.f + __expf(-x)); }
__device__ __forceinline__ float tanhf_fast(float x)    { return 1.f - 2.f / (__expf(2.f * x) + 1.f); }

// ---------- A conversion: Abf[b][k] = bf16(k<1024 ? X[b][k] : H[b][k-1024])
__global__ void conv_a_kernel(const float* __restrict__ X, const float* __restrict__ H,
                              unsigned short* __restrict__ Abf) {
  int idx = blockIdx.x * blockDim.x + threadIdx.x;
  int b  = idx >> 8;
  int kq = (idx & 255) << 2;
  float4 x = *(const float4*)(X + (long)b * 1024 + kq);
  float4 h = *(const float4*)(H + (long)b * 1024 + kq);
  ushort4 xo, ho;
  xo.x = f2bf(x.x); xo.y = f2bf(x.y); xo.z = f2bf(x.z); xo.w = f2bf(x.w);
  ho.x = f2bf(h.x); ho.y = f2bf(h.y); ho.z = f2bf(h.z); ho.w = f2bf(h.w);
  *(ushort4*)(Abf + (long)b * 2048 + kq)        = xo;
  *(ushort4*)(Abf + (long)b * 2048 + 1024 + kq) = ho;
}

// ---------- B conversion: Bt[n][k] bf16, N-major, n = (u>>4)*64 + g*16 + (u&15)
__global__ void conv_b_kernel(const float* W_i, const float* U_i,
                              const float* W_f, const float* U_f,
                              const float* W_c, const float* U_c,
                              const float* W_o, const float* U_o,
                              unsigned short* __restrict__ Bt) {
  __shared__ float tile[64][65];
  int z = blockIdx.z;
  const float* src;
  switch (z) {
    case 0: src = W_i; break; case 1: src = U_i; break;
    case 2: src = W_f; break; case 3: src = U_f; break;
    case 4: src = W_c; break; case 5: src = U_c; break;
    case 6: src = W_o; break; default: src = U_o; break;
  }
  int g = z >> 1, s = z & 1;
  int k0 = blockIdx.x * 64;
  int u0 = blockIdx.y * 64;
  int t = threadIdx.x;
  int c = t & 63, r0 = t >> 6;
#pragma unroll
  for (int i = 0; i < 16; ++i) {
    int r = i * 4 + r0;
    tile[r][c] = src[(long)(k0 + r) * 1024 + u0 + c];
  }
  __syncthreads();
  int ul = t >> 2;
  int ks = (t & 3) * 16;
  unsigned short outv[16];
#pragma unroll
  for (int j = 0; j < 16; ++j) outv[j] = f2bf(tile[ks + j][ul]);
  long n   = 4L * u0 + (ul >> 4) * 64 + g * 16 + (ul & 15);
  long col = (long)s * 1024 + k0 + ks;
  uint4* dst = (uint4*)(Bt + n * 2048 + col);
  dst[0] = *(uint4*)(outv);
  dst[1] = *(uint4*)(outv + 8);
}

// ---------- fused GEMM + LSTM epilogue
__global__ __launch_bounds__(512, 2) void lstm_gemm_kernel(
    const unsigned short* __restrict__ Abf,   // [8192][2048] bf16
    const unsigned short* __restrict__ Btbf,  // [4096][2048] bf16 (N-major)
    const float* __restrict__ b_i, const float* __restrict__ b_f,
    const float* __restrict__ b_c, const float* __restrict__ b_o,
    const float* __restrict__ c_tm1,
    float* __restrict__ outH, float* __restrict__ outC) {
  // 4 buffers x (A tile 256x32 + B tile 256x32) bf16 = 128KB
  __shared__ unsigned short smem[4 * 16384];

  int bid = blockIdx.x;
  int swz = (bid & 7) * 64 + (bid >> 3);  // XCD swizzle, 512 % 8 == 0
  int bm = swz >> 4;   // 32 m-blocks
  int bn = swz & 15;   // 16 n-blocks

  int t = threadIdx.x;
  int lane = t & 63;
  int w = t >> 6;           // 8 waves
  int wm = w >> 2;          // 0..1
  int wn = w & 3;           // 0..3
  int rl = lane & 15;
  int kg = lane >> 4;       // 0..3, 8-elem k-chunk

  // ---- ds_read element offsets (XOR chunk swizzle: chunk ^= (row>>1)&3) ----
#define AOFF(MI) ((wm * 128 + (MI) * 16 + rl) * 32 + \
    ((((kg * 16) ^ ((((wm * 128 + (MI) * 16 + rl) >> 1) & 3) << 4))) >> 1))
#define BOFF(NI) ((wn * 64 + (NI) * 16 + rl) * 32 + \
    ((((kg * 16) ^ ((((wn * 64 + (NI) * 16 + rl) >> 1) & 3) << 4))) >> 1))
  const int offA0 = AOFF(0), offA1 = AOFF(1), offA2 = AOFF(2), offA3 = AOFF(3);
  const int offA4 = AOFF(4), offA5 = AOFF(5), offA6 = AOFF(6), offA7 = AOFF(7);
  const int offB0 = 8192 + BOFF(0), offB1 = 8192 + BOFF(1);
  const int offB2 = 8192 + BOFF(2), offB3 = 8192 + BOFF(3);
#undef AOFF
#undef BOFF

  // ---- staging: linear LDS dest, inverse-swizzled global source ----
  int srow = t >> 2;
  int cbe  = (((t & 3) * 16) ^ (((srow >> 1) & 3) << 4)) >> 1;
  const unsigned short* aS0 = Abf  + (long)(bm * 256 + srow) * 2048 + cbe;
  const unsigned short* aS1 = aS0 + 128L * 2048;
  const unsigned short* bS0 = Btbf + (long)(bn * 256 + srow) * 2048 + cbe;
  const unsigned short* bS1 = bS0 + 128L * 2048;
  const int dstA0 = t * 8, dstA1 = 4096 + t * 8;
  const int dstB0 = 8192 + t * 8, dstB1 = 12288 + t * 8;

#define GLL(SRC, SB, DOFF)                                                                     \
  __builtin_amdgcn_global_load_lds((const __attribute__((address_space(1))) void*)(SRC),       \
      (__attribute__((address_space(3))) void*)(&smem[(SB) * 16384 + (DOFF)]), 16, 0, 0)

  f32x4 acc[8][4];
#pragma unroll
  for (int mi = 0; mi < 8; ++mi)
#pragma unroll
    for (int ni = 0; ni < 4; ++ni) acc[mi][ni] = (f32x4){0.f, 0.f, 0.f, 0.f};

  // fragment register sets: p (even tiles), q (odd tiles); ah = A rows 4-7, read in-tile
  short8 pa0, pa1, pa2, pa3, pb0, pb1, pb2, pb3;
  short8 qa0, qa1, qa2, qa3, qb0, qb1, qb2, qb3;
  short8 ah0, ah1, ah2, ah3;

  // ---- prologue: stage tiles 0,1,2 -> buf 0,1,2; wait tile 0; prefetch tile-0 frags ----
  GLL(aS0, 0, dstA0); GLL(aS1, 0, dstA1); GLL(bS0, 0, dstB0); GLL(bS1, 0, dstB1);
  GLL(aS0 + 32, 1, dstA0); GLL(aS1 + 32, 1, dstA1);
  GLL(bS0 + 32, 1, dstB0); GLL(bS1 + 32, 1, dstB1);
  GLL(aS0 + 64, 2, dstA0); GLL(aS1 + 64, 2, dstA1);
  GLL(bS0 + 64, 2, dstB0); GLL(bS1 + 64, 2, dstB1);
  asm volatile("s_waitcnt vmcnt(8)" ::: "memory");
  __builtin_amdgcn_s_barrier();
  pa0 = *(const short8*)(smem + offA0);
  pa1 = *(const short8*)(smem + offA1);
  pa2 = *(const short8*)(smem + offA2);
  pa3 = *(const short8*)(smem + offA3);
  pb0 = *(const short8*)(smem + offB0);
  pb1 = *(const short8*)(smem + offB1);
  pb2 = *(const short8*)(smem + offB2);
  pb3 = *(const short8*)(smem + offB3);
  aS0 += 96; aS1 += 96; bS0 += 96; bS1 += 96;   // staging base -> tile 3

#define MF4(AF, MI, BP)                                                                      \
  acc[MI][0] = __builtin_amdgcn_mfma_f32_16x16x32_bf16(AF, BP##0, acc[MI][0], 0, 0, 0);      \
  acc[MI][1] = __builtin_amdgcn_mfma_f32_16x16x32_bf16(AF, BP##1, acc[MI][1], 0, 0, 0);      \
  acc[MI][2] = __builtin_amdgcn_mfma_f32_16x16x32_bf16(AF, BP##2, acc[MI][2], 0, 0, 0);      \
  acc[MI][3] = __builtin_amdgcn_mfma_f32_16x16x32_bf16(AF, BP##3, acc[MI][3], 0, 0, 0);

// Tile T: consume set C (prefetched during T-1) + ah (read here); prefetch set N
// from buf NXT (tile T+1, landed via counted vmcnt); stage tile T+3 into buf STG.
// VMN: 4 = vmcnt(4)+barrier (steady), 0 = vmcnt(0)+barrier (tail drain), -1 = none.
#define ITER(BUF, STG, NXT, KOFF, C, N, DOSTAGE, DOPREF, VMN)                  \
  do {                                                                         \
    const unsigned short* Sr_ = smem + (BUF) * 16384;                          \
    ah0 = *(const short8*)(Sr_ + offA4);                                       \
    ah1 = *(const short8*)(Sr_ + offA5);                                       \
    ah2 = *(const short8*)(Sr_ + offA6);                                       \
    ah3 = *(const short8*)(Sr_ + offA7);                                       \
    __builtin_amdgcn_sched_barrier(0);                                         \
    __builtin_amdgcn_s_setprio(1);                                             \
    MF4(C##a0, 0, C##b) MF4(C##a1, 1, C##b)                                    \
    MF4(C##a2, 2, C##b) MF4(C##a3, 3, C##b)                                    \
    __builtin_amdgcn_s_setprio(0);                                             \
    __builtin_amdgcn_sched_barrier(0);                                         \
    if ((VMN) >= 0) {                                                          \
      if ((VMN) == 4) asm volatile("s_waitcnt vmcnt(4)" ::: "memory");         \
      else            asm volatile("s_waitcnt vmcnt(0)" ::: "memory");         \
      __builtin_amdgcn_s_barrier();                                            \
      __builtin_amdgcn_sched_barrier(0);                                       \
    }                                                                          \
    if (DOSTAGE) {                                                             \
      GLL(aS0 + (KOFF), (STG), dstA0); GLL(aS1 + (KOFF), (STG), dstA1);        \
      GLL(bS0 + (KOFF), (STG), dstB0); GLL(bS1 + (KOFF), (STG), dstB1);        \
    }                                                                          \
    if (DOPREF) {                                                              \
      const unsigned short* Sn_ = smem + (NXT) * 16384;                        \
      N##a0 = *(const short8*)(Sn_ + offA0);                                   \
      N##a1 = *(const short8*)(Sn_ + offA1);                                   \
      N##a2 = *(const short8*)(Sn_ + offA2);                                   \
      N##a3 = *(const short8*)(Sn_ + offA3);                                   \
      N##b0 = *(const short8*)(Sn_ + offB0);                                   \
      N##b1 = *(const short8*)(Sn_ + offB1);                                   \
      N##b2 = *(const short8*)(Sn_ + offB2);                                   \
      N##b3 = *(const short8*)(Sn_ + offB3);                                   \
    }                                                                          \
    __builtin_amdgcn_sched_barrier(0);                                         \
    __builtin_amdgcn_s_setprio(1);                                             \
    MF4(ah0, 4, C##b) MF4(ah1, 5, C##b)                                        \
    MF4(ah2, 6, C##b) MF4(ah3, 7, C##b)                                        \
    __builtin_amdgcn_s_setprio(0);                                             \
  } while (0)

  // Main: 15 groups of 4 tiles (T=0..59); tile T stages T+3, prefetches T+1.
  for (int g = 0; g < 15; ++g) {
    ITER(0, 3, 1, 0,  p, q, 1, 1, 4);
    ITER(1, 0, 2, 32, q, p, 1, 1, 4);
    ITER(2, 1, 3, 64, p, q, 1, 1, 4);
    ITER(3, 2, 0, 96, q, p, 1, 1, 4);
    aS0 += 128; aS1 += 128; bS0 += 128; bS1 += 128;
  }
  // Tail: base points at tile 63.
  ITER(0, 3, 1, 0, p, q, 1, 1, 4);   // T=60: stage tile 63 -> buf3
  ITER(1, 0, 2, 0, q, p, 0, 1, 4);   // T=61
  ITER(2, 1, 3, 0, p, q, 0, 1, 0);   // T=62: drain (tile 63 must land)
  ITER(3, 2, 0, 0, q, p, 0, 0, -1);  // T=63: pure compute
#undef ITER
#undef MF4
#undef GLL

  // ---- fused LSTM epilogue ----
  // Wave N-span = 64 cols = one u-block: u = nbase/4 + rl; gate = ni.
  int mbase = bm * 256 + wm * 128;
  int nbase = bn * 256 + wn * 64;
  int u = (nbase >> 2) + rl;
  float bi_v = b_i[u], bf_v = b_f[u], bc_v = b_c[u], bo_v = b_o[u];
  int rquad = (lane >> 4) << 2;
#pragma unroll
  for (int mi = 0; mi < 8; ++mi) {
#pragma unroll
    for (int j = 0; j < 4; ++j) {
      int brow = mbase + mi * 16 + rquad + j;
      float zi = acc[mi][0][j] + bi_v;
      float zf = acc[mi][1][j] + bf_v;
      float zc = acc[mi][2][j] + bc_v;
      float zo = acc[mi][3][j] + bo_v;
      float ig = sigmoidf_fast(zi);
      float fg = sigmoidf_fast(zf);
      float cg = tanhf_fast(zc);
      float og = sigmoidf_fast(zo);
      float cp = c_tm1[(long)brow * 1024 + u];
      float cn = fg * cp + ig * cg;
      float hn = og * tanhf_fast(cn);
      outH[(long)brow * 1024 + u] = hn;
      outC[(long)brow * 1024 + u] = cn;
    }
  }
}

extern "C" void kernel_launch(void* const* d_in, const int* in_sizes, int n_in,
                              void* d_out, int out_size, void* d_ws, size_t ws_size,
                              hipStream_t stream) {
  (void)in_sizes; (void)n_in; (void)out_size; (void)ws_size;
  const float* X   = (const float*)d_in[0];
  const float* Hst = (const float*)d_in[1];
  const float* Cst = (const float*)d_in[2];
  const float* W_i = (const float*)d_in[3];
  const float* U_i = (const float*)d_in[4];
  const float* b_i = (const float*)d_in[5];
  const float* W_f = (const float*)d_in[6];
  const float* U_f = (const float*)d_in[7];
  const float* b_f = (const float*)d_in[8];
  const float* W_c = (const float*)d_in[9];
  const float* U_c = (const float*)d_in[10];
  const float* b_c = (const float*)d_in[11];
  const float* W_o = (const float*)d_in[12];
  const float* U_o = (const float*)d_in[13];
  const float* b_o = (const float*)d_in[14];

  unsigned short* Abf  = (unsigned short*)d_ws;                        // 32 MB
  unsigned short* Btbf = (unsigned short*)((char*)d_ws + 33554432);    // 16 MB

  float* outH = (float*)d_out;
  float* outC = outH + 8192L * 1024;

  conv_a_kernel<<<8192, 256, 0, stream>>>(X, Hst, Abf);
  conv_b_kernel<<<dim3(16, 16, 8), 256, 0, stream>>>(W_i, U_i, W_f, U_f, W_c, U_c, W_o, U_o, Btbf);
  lstm_gemm_kernel<<<512, 512, 0, stream>>>(Abf, Btbf, b_i, b_f, b_c, b_o, Cst, outH, outC);
}